// Round 1
// baseline (272.137 us; speedup 1.0000x reference)
//
#include <hip/hip_runtime.h>
#include <hip/hip_bf16.h>

typedef __bf16 bf16;
typedef __attribute__((ext_vector_type(8))) __bf16 bf16x8;
typedef __attribute__((ext_vector_type(4))) __bf16 bf16x4;
typedef __attribute__((ext_vector_type(4))) float f32x4;

#define NEGV (-1e18f)

__device__ __forceinline__ bf16 f2b(float f) {
    // round-to-nearest-even f32->bf16; inputs are finite Gaussians (no NaN/Inf path needed)
    unsigned u = __builtin_bit_cast(unsigned, f);
    u += 0x7fffu + ((u >> 16) & 1u);
    unsigned short h = (unsigned short)(u >> 16);
    return __builtin_bit_cast(bf16, h);
}

__device__ __forceinline__ f32x4 mfma16(bf16x8 a, bf16x8 b, f32x4 c) {
    return __builtin_amdgcn_mfma_f32_16x16x32_bf16(a, b, c, 0, 0, 0);
}

// ---------------------------------------------------------------------------
// Weight transpose + f32->bf16 convert: out[w][n][k] = in[w][k][n]
// grid (16,16,4) blocks of 256; 64x64 tiles via LDS (pad 65 -> 2-way banks)
// ---------------------------------------------------------------------------
__global__ __launch_bounds__(256) void wconv(const float* __restrict__ W0,
                                             const float* __restrict__ W1,
                                             const float* __restrict__ W2,
                                             const float* __restrict__ W3,
                                             bf16* __restrict__ out) {
    __shared__ float tile[64][65];
    const float* Ws[4] = {W0, W1, W2, W3};
    const float* W = Ws[blockIdx.z];
    bf16* O = out + ((size_t)blockIdx.z << 20);
    int t = threadIdx.x;
    int k0 = blockIdx.x * 64, n0 = blockIdx.y * 64;
#pragma unroll
    for (int p = 0; p < 4; p++) {
        int r = (t >> 4) + p * 16, c = (t & 15) * 4;
        float4 v = *(const float4*)&W[(size_t)(k0 + r) * 1024 + n0 + c];
        tile[r][c] = v.x; tile[r][c + 1] = v.y; tile[r][c + 2] = v.z; tile[r][c + 3] = v.w;
    }
    __syncthreads();
#pragma unroll
    for (int p = 0; p < 4; p++) {
        int r = (t >> 4) + p * 16, c = (t & 15) * 4;  // r = out row (n), c = out col (k)
        bf16x4 o;
        o[0] = f2b(tile[c][r]); o[1] = f2b(tile[c + 1][r]);
        o[2] = f2b(tile[c + 2][r]); o[3] = f2b(tile[c + 3][r]);
        *(bf16x4*)&O[(size_t)(n0 + r) * 1024 + k0 + c] = o;
    }
}

// ---------------------------------------------------------------------------
// Unified MFMA GEMM, 128x128 tile, BK=32, 256 threads (4 waves, 2x2 of 64x64).
// C[m,n] = sum_k A[m,k] * Bt[n,k]   (Bt is row-major over n; i.e. B transposed)
// MODE 0: A=f32 (activations), C=bf16, C *= scale      (projections)
// MODE 1: A=bf16, C=f32                                 (ctx @ Wo)
// MODE 2: batched (z=b): A=Q[b], Bt=K[b], C=f32 aw with mask->NEG, /16
// LDS row stride 56 elems = 112B = 7*16B -> b128-aligned, 2-way banks (free).
// ---------------------------------------------------------------------------
template <int MODE>
__global__ __launch_bounds__(256) void gemm_k(const void* __restrict__ Ap,
                                              const bf16* __restrict__ Btp,
                                              void* __restrict__ Cp,
                                              const int* __restrict__ maskp,
                                              float scale) {
    __shared__ bf16 As[128][56];
    __shared__ bf16 Bs[128][56];
    int t = threadIdx.x;
    int m0 = blockIdx.x * 128, n0 = blockIdx.y * 128;
    const float* Af = (const float*)Ap;
    const bf16* Ab = (const bf16*)Ap;
    const bf16* Bt = Btp;
    float* Cf = (float*)Cp;
    bf16* Cb = (bf16*)Cp;
    const int* mask = maskp;
    if (MODE == 2) {
        size_t z = blockIdx.z;
        Ab += z << 20; Bt += z << 20; Cf += z << 20; mask += z * 1024;
    }
    int wid = t >> 6, lane = t & 63;
    int wr = wid >> 1, wc = wid & 1, lr = lane & 15, lg = lane >> 4;
    f32x4 zero = {0.f, 0.f, 0.f, 0.f};
    f32x4 acc[4][4];
#pragma unroll
    for (int m = 0; m < 4; m++)
#pragma unroll
        for (int n = 0; n < 4; n++) acc[m][n] = zero;

    for (int k0 = 0; k0 < 1024; k0 += 32) {
        __syncthreads();
        if (MODE == 0) {
#pragma unroll
            for (int p = 0; p < 4; p++) {
                int r = (t >> 3) + p * 32, kk = (t & 7) * 4;
                float4 v = *(const float4*)&Af[(size_t)(m0 + r) * 1024 + k0 + kk];
                bf16x4 o;
                o[0] = f2b(v.x); o[1] = f2b(v.y); o[2] = f2b(v.z); o[3] = f2b(v.w);
                *(bf16x4*)&As[r][kk] = o;
            }
        } else {
#pragma unroll
            for (int p = 0; p < 2; p++) {
                int r = (t >> 2) + p * 64, kk = (t & 3) * 8;
                *(bf16x8*)&As[r][kk] = *(const bf16x8*)&Ab[(size_t)(m0 + r) * 1024 + k0 + kk];
            }
        }
#pragma unroll
        for (int p = 0; p < 2; p++) {
            int r = (t >> 2) + p * 64, kk = (t & 3) * 8;
            *(bf16x8*)&Bs[r][kk] = *(const bf16x8*)&Bt[(size_t)(n0 + r) * 1024 + k0 + kk];
        }
        __syncthreads();
        bf16x8 af[4], bfr[4];
#pragma unroll
        for (int m = 0; m < 4; m++) af[m] = *(const bf16x8*)&As[wr * 64 + m * 16 + lr][lg * 8];
#pragma unroll
        for (int n = 0; n < 4; n++) bfr[n] = *(const bf16x8*)&Bs[wc * 64 + n * 16 + lr][lg * 8];
#pragma unroll
        for (int m = 0; m < 4; m++)
#pragma unroll
            for (int n = 0; n < 4; n++) acc[m][n] = mfma16(af[m], bfr[n], acc[m][n]);
    }
    // epilogue: D row=(lg*4+j), col=lr within each 16x16 frag
#pragma unroll
    for (int n = 0; n < 4; n++) {
        int colg = n0 + wc * 64 + n * 16 + lr;
        int mk = (MODE == 2) ? mask[colg] : 0;
#pragma unroll
        for (int m = 0; m < 4; m++) {
            int rowg = m0 + wr * 64 + m * 16 + lg * 4;
#pragma unroll
            for (int j = 0; j < 4; j++) {
                float v = acc[m][n][j];
                size_t idx = (size_t)(rowg + j) * 1024 + colg;
                if (MODE == 0) Cb[idx] = f2b(v * scale);
                else if (MODE == 1) Cf[idx] = v;
                else Cf[idx] = mk ? NEGV : v * (1.f / 16.f);
            }
        }
    }
}

// ---------------------------------------------------------------------------
// Flash attention per (b, h, 64-row q-tile). 4 waves x 16 q-rows each.
// K staged [128][72] (144B rows), V staged transposed [64][136] (272B rows),
// P relayout via per-wave LDS [16][136]. Online softmax with shfl over lr.
// ---------------------------------------------------------------------------
__global__ __launch_bounds__(256) void flash_k(const bf16* __restrict__ Q,
                                               const bf16* __restrict__ K,
                                               const bf16* __restrict__ V,
                                               bf16* __restrict__ CTX,
                                               const int* __restrict__ maskp) {
    __shared__ bf16 Ks[128][72];
    __shared__ bf16 Vt[64][136];
    __shared__ bf16 Ps[4][16][136];
    int bid = blockIdx.x;
    int qt = bid & 15, h = (bid >> 4) & 15, b = bid >> 8;
    int t = threadIdx.x, wid = t >> 6, lane = t & 63;
    int lr = lane & 15, lg = lane >> 4;
    int qbase = qt * 64 + wid * 16;
    const size_t bS = (size_t)b * 1024;

    bf16x8 qf[2];
#pragma unroll
    for (int c = 0; c < 2; c++)
        qf[c] = *(const bf16x8*)&Q[(bS + qbase + lr) * 1024 + h * 64 + c * 32 + lg * 8];

    f32x4 zero = {0.f, 0.f, 0.f, 0.f};
    f32x4 acc[4];
#pragma unroll
    for (int d = 0; d < 4; d++) acc[d] = zero;
    float mrow[4] = {-INFINITY, -INFINITY, -INFINITY, -INFINITY};
    float lrow[4] = {0.f, 0.f, 0.f, 0.f};

    for (int kt = 0; kt < 8; kt++) {
        __syncthreads();
#pragma unroll
        for (int p = 0; p < 4; p++) {
            int r = (t >> 3) + p * 32, kd = (t & 7) * 8;
            const size_t g = (bS + kt * 128 + r) * 1024 + h * 64 + kd;
            *(bf16x8*)&Ks[r][kd] = *(const bf16x8*)&K[g];
            bf16x8 v = *(const bf16x8*)&V[g];
#pragma unroll
            for (int j = 0; j < 8; j++) Vt[kd + j][r] = v[j];
        }
        __syncthreads();

        // scores: S[q=lg*4+j][kcol=n*16+lr]
        f32x4 s[8];
#pragma unroll
        for (int n = 0; n < 8; n++) {
            bf16x8 kf0 = *(const bf16x8*)&Ks[n * 16 + lr][lg * 8];
            bf16x8 kf1 = *(const bf16x8*)&Ks[n * 16 + lr][32 + lg * 8];
            f32x4 z = zero;
            z = mfma16(qf[0], kf0, z);
            z = mfma16(qf[1], kf1, z);
            s[n] = z;
        }
#pragma unroll
        for (int n = 0; n < 8; n++) {
            int mk = maskp[b * 1024 + kt * 128 + n * 16 + lr];
            if (mk) { s[n][0] = NEGV; s[n][1] = NEGV; s[n][2] = NEGV; s[n][3] = NEGV; }
        }
        // online softmax per q-row (rows lg*4+j; reduce across lr via xor 1,2,4,8)
#pragma unroll
        for (int j = 0; j < 4; j++) {
            float mj = s[0][j];
#pragma unroll
            for (int n = 1; n < 8; n++) mj = fmaxf(mj, s[n][j]);
            mj = fmaxf(mj, __shfl_xor(mj, 1));
            mj = fmaxf(mj, __shfl_xor(mj, 2));
            mj = fmaxf(mj, __shfl_xor(mj, 4));
            mj = fmaxf(mj, __shfl_xor(mj, 8));
            float mn = fmaxf(mrow[j], mj);
            float sc = __expf(mrow[j] - mn);
            mrow[j] = mn;
            float rs = 0.f;
#pragma unroll
            for (int n = 0; n < 8; n++) {
                float pv = __expf(s[n][j] - mn);
                s[n][j] = pv;
                rs += pv;
            }
            rs += __shfl_xor(rs, 1);
            rs += __shfl_xor(rs, 2);
            rs += __shfl_xor(rs, 4);
            rs += __shfl_xor(rs, 8);
            lrow[j] = lrow[j] * sc + rs;
#pragma unroll
            for (int d = 0; d < 4; d++) acc[d][j] *= sc;
        }
        // P -> per-wave LDS (bf16), then PV via MFMA
#pragma unroll
        for (int n = 0; n < 8; n++)
#pragma unroll
            for (int j = 0; j < 4; j++) Ps[wid][lg * 4 + j][n * 16 + lr] = f2b(s[n][j]);
#pragma unroll
        for (int c = 0; c < 4; c++) {
            bf16x8 pa = *(const bf16x8*)&Ps[wid][lr][c * 32 + lg * 8];
#pragma unroll
            for (int d = 0; d < 4; d++) {
                bf16x8 vb = *(const bf16x8*)&Vt[d * 16 + lr][c * 32 + lg * 8];
                acc[d] = mfma16(pa, vb, acc[d]);
            }
        }
    }
    // epilogue: ctx[b, qbase+lg*4+j, h*64 + d*16 + lr]
#pragma unroll
    for (int j = 0; j < 4; j++) {
        float inv = 1.f / lrow[j];
#pragma unroll
        for (int d = 0; d < 4; d++)
            CTX[(bS + qbase + lg * 4 + j) * 1024 + h * 64 + d * 16 + lr] = f2b(acc[d][j] * inv);
    }
}

extern "C" void kernel_launch(void* const* d_in, const int* in_sizes, int n_in,
                              void* d_out, int out_size, void* d_ws, size_t ws_size,
                              hipStream_t stream) {
    const float* queries = (const float*)d_in[0];
    const float* keys    = (const float*)d_in[1];
    const float* values  = (const float*)d_in[2];
    const float* Wq = (const float*)d_in[3];
    const float* Wk = (const float*)d_in[4];
    const float* Wv = (const float*)d_in[5];
    const float* Wo = (const float*)d_in[6];
    const int* mask = (const int*)d_in[7];

    float* out = (float*)d_out;                       // [4,1024,1024]
    float* aw  = out + ((size_t)4 << 20);             // [4,1024,1024]

    bf16* wsb = (bf16*)d_ws;
    bf16* WtQ = wsb;                                  // 4 x 1M bf16 (transposed weights)
    bf16* Qw  = wsb + ((size_t)4 << 20);              // [4096,1024] bf16 (scaled)
    bf16* Kw  = wsb + ((size_t)8 << 20);
    bf16* Vw  = wsb + ((size_t)12 << 20);
    bf16* CTX = wsb + ((size_t)16 << 20);

    wconv<<<dim3(16, 16, 4), 256, 0, stream>>>(Wq, Wk, Wv, Wo, WtQ);
    gemm_k<0><<<dim3(32, 8, 1), 256, 0, stream>>>(queries, WtQ, Qw, nullptr, 0.125f);
    gemm_k<0><<<dim3(32, 8, 1), 256, 0, stream>>>(keys, WtQ + (1u << 20), Kw, nullptr, 1.0f);
    gemm_k<0><<<dim3(32, 8, 1), 256, 0, stream>>>(values, WtQ + (2u << 20), Vw, nullptr, 1.0f);
    gemm_k<2><<<dim3(8, 8, 4), 256, 0, stream>>>(Qw, Kw, aw, mask, 1.0f);
    flash_k<<<dim3(1024), 256, 0, stream>>>(Qw, Kw, Vw, CTX, mask);
    gemm_k<1><<<dim3(32, 8, 1), 256, 0, stream>>>(CTX, WtQ + (3u << 20), out, nullptr, 1.0f);
}